// Round 1
// baseline (255.420 us; speedup 1.0000x reference)
//
#include <hip/hip_runtime.h>
#include <hip/hip_bf16.h>

// HierarchicalRouter: x[16384,2048] fp32, group_gate_w[8,2048], expert_gate_w[64,2048]
// out = concat(valid_mask[16384,64] as 0/1 float, normalized_weights[16384,64] float)
//
// Phase A: fp32 register-tiled GEMM computing all 72 logits per token.
//   Block: 256 threads = 32 token-cols (8 tokens each) x 8 gate-rows (8 experts + 1 group gate each).
//   BM=256 tokens, K split into S chunks across blocks -> 64*S blocks. Partials to d_ws.
// Phase B: one thread per token: reduce S partials, dual softmax, mask, normalize, write.

#define N_TOKENS 16384
#define N_EMBD   2048
#define BK       16

__global__ __launch_bounds__(256, 2)
void routerA(const float* __restrict__ x, const float* __restrict__ gw,
             const float* __restrict__ ew, float* __restrict__ P,
             int S, int KC)
{
    __shared__ float xs[BK][256];  // [k][token]  16 KB
    __shared__ float es[BK][64];   // [k][expert]  4 KB
    __shared__ float gs[BK][8];    // [k][group]  0.5 KB

    const int tid = threadIdx.x;
    const int ks  = blockIdx.x % S;       // K-split index
    const int tb  = blockIdx.x / S;       // token block
    const int t0  = tb * 256;
    const int col = tid & 31;             // token group (8 tokens)
    const int row = tid >> 5;             // gate row: experts row*8..+7, group gate `row`

    float accE[8][8];
    float accG[8];
    #pragma unroll
    for (int i = 0; i < 8; ++i) {
        accG[i] = 0.f;
        #pragma unroll
        for (int j = 0; j < 8; ++j) accE[i][j] = 0.f;
    }

    const int k0    = ks * KC;
    const int niter = KC >> 4;            // KC / BK

    // staging pointers (per-thread constant)
    const float* xg = x + (size_t)(t0 + tid) * N_EMBD + k0;        // 16 floats/iter
    const int we = tid & 63, wj = tid >> 6;                        // expert row, k-quad
    const float* eg = ew + (size_t)we * N_EMBD + k0 + wj * 4;      // 4 floats/iter
    const int gg = tid & 7, gj = tid >> 3;                         // (tid<32 only)
    const float* gp = gw + (size_t)gg * N_EMBD + k0 + gj * 4;

    for (int it = 0; it < niter; ++it) {
        const int kb = it * BK;
        // ---- stage x (transpose into xs[k][token]) ----
        #pragma unroll
        for (int j = 0; j < 4; ++j) {
            float4 v = *(const float4*)(xg + kb + 4 * j);
            xs[4*j+0][tid] = v.x; xs[4*j+1][tid] = v.y;
            xs[4*j+2][tid] = v.z; xs[4*j+3][tid] = v.w;
        }
        // ---- stage expert gates ----
        {
            float4 v = *(const float4*)(eg + kb);
            es[wj*4+0][we] = v.x; es[wj*4+1][we] = v.y;
            es[wj*4+2][we] = v.z; es[wj*4+3][we] = v.w;
        }
        // ---- stage group gates ----
        if (tid < 32) {
            float4 v = *(const float4*)(gp + kb);
            gs[gj*4+0][gg] = v.x; gs[gj*4+1][gg] = v.y;
            gs[gj*4+2][gg] = v.z; gs[gj*4+3][gg] = v.w;
        }
        __syncthreads();

        #pragma unroll 4
        for (int kk = 0; kk < BK; ++kk) {
            float4 a = *(const float4*)&xs[kk][col * 8];
            float4 b = *(const float4*)&xs[kk][col * 8 + 4];
            float4 c = *(const float4*)&es[kk][row * 8];
            float4 d = *(const float4*)&es[kk][row * 8 + 4];
            float  g = gs[kk][row];
            float xv[8] = {a.x, a.y, a.z, a.w, b.x, b.y, b.z, b.w};
            float wv[8] = {c.x, c.y, c.z, c.w, d.x, d.y, d.z, d.w};
            #pragma unroll
            for (int i = 0; i < 8; ++i) {
                #pragma unroll
                for (int j = 0; j < 8; ++j)
                    accE[i][j] = fmaf(xv[i], wv[j], accE[i][j]);
                accG[i] = fmaf(xv[i], g, accG[i]);
            }
        }
        __syncthreads();
    }

    // ---- epilogue: partial logits P[ks][t][0..63]=experts, [64..71]=group ----
    #pragma unroll
    for (int i = 0; i < 8; ++i) {
        const int t = t0 + col * 8 + i;
        float* p = P + ((size_t)ks * N_TOKENS + t) * 72;
        *(float4*)(p + row * 8)     = make_float4(accE[i][0], accE[i][1], accE[i][2], accE[i][3]);
        *(float4*)(p + row * 8 + 4) = make_float4(accE[i][4], accE[i][5], accE[i][6], accE[i][7]);
        p[64 + row] = accG[i];
    }
}

__global__ __launch_bounds__(256)
void routerB(const float* __restrict__ P, float* __restrict__ out, int S)
{
    const int t = blockIdx.x * 256 + threadIdx.x;

    float l[72];
    #pragma unroll
    for (int i = 0; i < 72; ++i) l[i] = 0.f;
    for (int s = 0; s < S; ++s) {
        const float4* p = (const float4*)(P + ((size_t)s * N_TOKENS + t) * 72);
        #pragma unroll
        for (int i = 0; i < 18; ++i) {
            float4 v = p[i];
            l[4*i+0] += v.x; l[4*i+1] += v.y; l[4*i+2] += v.z; l[4*i+3] += v.w;
        }
    }

    // group softmax (logits l[64..71]); temperature = 1
    float gpb[8];
    float gmax = l[64];
    #pragma unroll
    for (int g = 1; g < 8; ++g) gmax = fmaxf(gmax, l[64 + g]);
    float gsum = 0.f;
    #pragma unroll
    for (int g = 0; g < 8; ++g) { gpb[g] = expf(l[64 + g] - gmax); gsum += gpb[g]; }
    #pragma unroll
    for (int g = 0; g < 8; ++g) gpb[g] = gpb[g] / gsum;

    // per-group expert softmax; store selected weight into l[0..63]
    float wsum = 0.f;
    #pragma unroll
    for (int g = 0; g < 8; ++g) {
        float emax = l[g * 8];
        #pragma unroll
        for (int j = 1; j < 8; ++j) emax = fmaxf(emax, l[g * 8 + j]);
        float ep[8]; float esum = 0.f;
        #pragma unroll
        for (int j = 0; j < 8; ++j) { ep[j] = expf(l[g * 8 + j] - emax); esum += ep[j]; }
        const bool gm = gpb[g] >= 0.125f;
        #pragma unroll
        for (int j = 0; j < 8; ++j) {
            float pe = ep[j] / esum;
            bool v = gm && (pe >= 0.125f);
            float ww = v ? gpb[g] * pe : 0.f;
            l[g * 8 + j] = ww;
            wsum += ww;
        }
    }
    wsum = fmaxf(wsum, 1e-9f);

    float* o0 = out + (size_t)t * 64;                       // valid mask (0/1 float)
    float* o1 = out + (size_t)N_TOKENS * 64 + (size_t)t * 64; // normalized weights
    #pragma unroll
    for (int i = 0; i < 16; ++i) {
        float4 vm, wn;
        vm.x = (l[4*i+0] != 0.f) ? 1.f : 0.f;  wn.x = l[4*i+0] / wsum;
        vm.y = (l[4*i+1] != 0.f) ? 1.f : 0.f;  wn.y = l[4*i+1] / wsum;
        vm.z = (l[4*i+2] != 0.f) ? 1.f : 0.f;  wn.z = l[4*i+2] / wsum;
        vm.w = (l[4*i+3] != 0.f) ? 1.f : 0.f;  wn.w = l[4*i+3] / wsum;
        *(float4*)(o0 + 4 * i) = vm;
        *(float4*)(o1 + 4 * i) = wn;
    }
}

extern "C" void kernel_launch(void* const* d_in, const int* in_sizes, int n_in,
                              void* d_out, int out_size, void* d_ws, size_t ws_size,
                              hipStream_t stream) {
    const float* x  = (const float*)d_in[0];
    const float* gw = (const float*)d_in[1];
    const float* ew = (const float*)d_in[2];
    float* out = (float*)d_out;
    float* P   = (float*)d_ws;

    // K-split factor: prefer 8 (512 blocks, 2 blocks/CU); shrink if workspace is small.
    int S = 8;
    while (S > 1 && (size_t)S * N_TOKENS * 72 * sizeof(float) > ws_size) S >>= 1;
    const int KC = N_EMBD / S;

    routerA<<<dim3(64 * S), dim3(256), 0, stream>>>(x, gw, ew, P, S, KC);
    routerB<<<dim3(N_TOKENS / 256), dim3(256), 0, stream>>>(P, out, S);
}